// Round 3
// baseline (664.483 us; speedup 1.0000x reference)
//
#include <hip/hip_runtime.h>
#include <cmath>

typedef _Float16 f16;
typedef _Float16 f16x4 __attribute__((ext_vector_type(4)));
typedef _Float16 f16x8 __attribute__((ext_vector_type(8)));
typedef float f32x4 __attribute__((ext_vector_type(4)));

// Dims: V=32000 E=256 H=256 B=64 S=32 T=32; decoder hidden 2H=512.

// ---------------- workspace layout (bytes) ----------------
static constexpr size_t OFF_WIHF = 0;                                 // 768x256 f16
static constexpr size_t OFF_WHHF = OFF_WIHF + 768UL*256*2;
static constexpr size_t OFF_WIHB = OFF_WHHF + 768UL*256*2;
static constexpr size_t OFF_WHHB = OFF_WIHB + 768UL*256*2;
static constexpr size_t OFF_WIHD = OFF_WHHB + 768UL*256*2;            // 1536x768 f16
static constexpr size_t OFF_WHHD = OFF_WIHD + 1536UL*768*2;           // 1536x512 f16
static constexpr size_t OFF_FCW  = OFF_WHHD + 1536UL*512*2;           // 32000x512 f16
static constexpr size_t OFF_XENC = OFF_FCW  + 32000UL*512*2;          // 2048x256 f16
static constexpr size_t OFF_XDEC = OFF_XENC + 2048UL*256*2;           // 1984x256 f16
static constexpr size_t OFF_GIF  = OFF_XDEC + 1984UL*256*2;           // 2048x768 f32
static constexpr size_t OFF_GIB  = OFF_GIF  + 2048UL*768*4;
static constexpr size_t OFF_GITOK= OFF_GIB  + 2048UL*768*4;           // 1984x1536 f32
static constexpr size_t OFF_GICTX= OFF_GITOK+ 1984UL*1536*4;          // 64x1536 f32
static constexpr size_t OFF_CTX32= OFF_GICTX+ 64UL*1536*4;            // 64x512 f32
static constexpr size_t OFF_CTX16= OFF_CTX32+ 64UL*512*4;             // 64x512 f16
static constexpr size_t OFF_HPP  = OFF_CTX16+ 64UL*512*2;             // 2dir x 2buf x 64x256 f16
static constexpr size_t OFF_HALL = OFF_HPP  + 2UL*2*64*256*2;         // 2048x512 f16 (rows>=1984 unused)
static constexpr size_t OFF_BAR  = OFF_HALL + 2048UL*512*2;           // 1024 ints (flag barrier)

__device__ __forceinline__ float sigmoidf_(float x) {
  return __builtin_amdgcn_rcpf(1.f + __expf(-x));
}
__device__ __forceinline__ float tanhf_(float x) {
  float xc = fminf(fmaxf(x, -10.f), 10.f);
  float e = __expf(2.f * xc);
  return (e - 1.f) * __builtin_amdgcn_rcpf(e + 1.f);
}

// sc1 (device-coherent) helpers: all cross-WG data moves through L3 only.
__device__ __forceinline__ f16x8 ld_h8(const f16* p) {
  union { unsigned u[4]; f16x8 v; } t;
  const unsigned* q = (const unsigned*)p;
#pragma unroll
  for (int k = 0; k < 4; k++)
    t.u[k] = __hip_atomic_load(q + k, __ATOMIC_RELAXED, __HIP_MEMORY_SCOPE_AGENT);
  return t.v;
}
__device__ __forceinline__ void st_h4(f16* p, float a, float b, float c, float d) {
  union { unsigned long long u; f16 h[4]; } t;
  t.h[0] = (f16)a; t.h[1] = (f16)b; t.h[2] = (f16)c; t.h[3] = (f16)d;
  __hip_atomic_store((unsigned long long*)p, t.u, __ATOMIC_RELAXED, __HIP_MEMORY_SCOPE_AGENT);
}
__device__ __forceinline__ void st_z8(f16* p) {
  __hip_atomic_store((unsigned long long*)p, 0ULL, __ATOMIC_RELAXED, __HIP_MEMORY_SCOPE_AGENT);
}

// Fence-free flag barrier: WG `self` stores its flag (sc1), wave 0 polls all
// n flags in parallel lanes. __syncthreads() drains vmcnt (h stores at L3).
__device__ __forceinline__ void fbar(int* flags, int self, int n, int target) {
  __syncthreads();  // emits s_waitcnt vmcnt(0) before s_barrier -> h stores done
  if (threadIdx.x < 64) {
    if (threadIdx.x == 0)
      __hip_atomic_store(flags + self * 16, target, __ATOMIC_RELAXED, __HIP_MEMORY_SCOPE_AGENT);
    int lane = threadIdx.x;
    while (true) {
      int v = (lane < n) ? __hip_atomic_load(flags + lane * 16, __ATOMIC_RELAXED, __HIP_MEMORY_SCOPE_AGENT)
                         : target;
      if (__all(v >= target)) break;
      __builtin_amdgcn_s_sleep(1);
    }
  }
  __syncthreads();
}

// ---------------- K1: fp32 -> fp16 weight conversion ----------------
__global__ void k_convert(const float* __restrict__ wihf, const float* __restrict__ whhf,
                          const float* __restrict__ wihb, const float* __restrict__ whhb,
                          const float* __restrict__ wihd, const float* __restrict__ whhd,
                          const float* __restrict__ fcw,
                          f16* dWihf, f16* dWhhf, f16* dWihb, f16* dWhhb,
                          f16* dWihd, f16* dWhhd, f16* dFcw) {
  const long stride = (long)gridDim.x * blockDim.x;
  for (long i = (long)blockIdx.x * blockDim.x + threadIdx.x; i < 4784128L; i += stride) {
    const float* s; f16* d; long j = i;
    if (j < 49152L)        { s = wihf; d = dWihf; }
    else if (j < 98304L)   { s = whhf; d = dWhhf; j -= 49152L; }
    else if (j < 147456L)  { s = wihb; d = dWihb; j -= 98304L; }
    else if (j < 196608L)  { s = whhb; d = dWhhb; j -= 147456L; }
    else if (j < 491520L)  { s = wihd; d = dWihd; j -= 196608L; }
    else if (j < 688128L)  { s = whhd; d = dWhhd; j -= 491520L; }
    else                   { s = fcw;  d = dFcw;  j -= 688128L; }
    float4 v = ((const float4*)s)[j];
    f16x4 o; o.x = (f16)v.x; o.y = (f16)v.y; o.z = (f16)v.z; o.w = (f16)v.w;
    ((f16x4*)d)[j] = o;
  }
}

// ---------------- K2: embedding gather + zero out[:,0,:] + flag init ----------------
__global__ void k_gather(const int* __restrict__ srct, const int* __restrict__ trgt,
                         const float* __restrict__ embe, const float* __restrict__ embd,
                         f16* __restrict__ Xenc, f16* __restrict__ Xdec,
                         float* __restrict__ out, int* __restrict__ bar) {
  long tid = (long)blockIdx.x * blockDim.x + threadIdx.x;
  long stride = (long)gridDim.x * blockDim.x;
  if (tid < 1024) bar[tid] = 0;
  for (long i = tid; i < 4032L * 64; i += stride) {
    int row = (int)(i >> 6), j4 = (int)(i & 63);
    const float* e; f16* d; int tok;
    if (row < 2048) {
      int s = row >> 6, b = row & 63;
      tok = srct[b * 32 + s]; e = embe; d = Xenc + (long)row * 256;
    } else {
      int rd = row - 2048; int t = rd >> 6, b = rd & 63;
      tok = trgt[b * 32 + t]; e = embd; d = Xdec + (long)rd * 256;
    }
    float4 v = ((const float4*)(e + (long)tok * 256))[j4];
    f16x4 o; o.x = (f16)v.x; o.y = (f16)v.y; o.z = (f16)v.z; o.w = (f16)v.w;
    ((f16x4*)d)[j4] = o;
  }
  for (long i = tid; i < 64L * 8000; i += stride) {
    long b = i / 8000, j = i % 8000;
    float4 z = make_float4(0.f, 0.f, 0.f, 0.f);
    ((float4*)(out + b * 1024000L))[j] = z;
  }
}

// ---------------- K3: generic small GEMM  C[M,N] = A[M,K]f16 @ B[N,K]f16^T (+bias) ----------------
__global__ __launch_bounds__(256) void k_gemm(const f16* __restrict__ A, int lda,
                                              const f16* __restrict__ B, int ldb,
                                              const float* __restrict__ bias,
                                              float* __restrict__ C, int ldc, int Ksteps) {
  int m0 = blockIdx.x * 64, n0 = blockIdx.y * 64;
  int lane = threadIdx.x & 63, w = threadIdx.x >> 6;
  int ar = m0 + w * 16 + (lane & 15);
  int koff = (lane >> 4) * 8;
  f32x4 acc[4] = {};
  for (int ks = 0; ks < Ksteps; ks++) {
    f16x8 a = *(const f16x8*)(A + (size_t)ar * lda + ks * 32 + koff);
#pragma unroll
    for (int ni = 0; ni < 4; ni++) {
      const f16* bp = B + (size_t)(n0 + ni * 16 + (lane & 15)) * ldb + ks * 32 + koff;
      f16x8 b = *(const f16x8*)bp;
      acc[ni] = __builtin_amdgcn_mfma_f32_16x16x32_f16(a, b, acc[ni], 0, 0, 0);
    }
  }
  int dm = m0 + w * 16 + ((lane >> 4) << 2);
  int dn0 = n0 + (lane & 15);
#pragma unroll
  for (int ni = 0; ni < 4; ni++) {
    int n = dn0 + ni * 16;
    float bv = bias ? bias[n] : 0.f;
#pragma unroll
    for (int r = 0; r < 4; r++) C[(size_t)(dm + r) * ldc + n] = acc[ni][r] + bv;
  }
}

// ---------------- K4: encoder bidir GRU recurrence (16 WGs x 256 thr) ----------------
// Swapped operands: mfma(W_frag, h_frag) -> lane holds batch row m = lane&15,
// 4 consecutive hidden cols per acc reg. Weights register-resident (asm keepalive).
__global__ __launch_bounds__(256, 1) void k_enc(
    const float* __restrict__ giF, const float* __restrict__ giB,
    const f16* __restrict__ WhhF, const f16* __restrict__ WhhB,
    const float* __restrict__ bhhF, const float* __restrict__ bhhB,
    f16* __restrict__ hpp, float* __restrict__ ctx32, f16* __restrict__ ctx16,
    int* __restrict__ bar) {
  int wg = blockIdx.x;
  int dir = wg >> 3, w8 = wg & 7;
  int tid = threadIdx.x, lane = tid & 63, wv = tid >> 6;
  int w2 = w8 * 4 + wv;                 // wave in dir: [0,32)
  int mTile = w2 >> 3;                  // 4 m-tiles of 16 rows
  int ns = w2 & 7;                      // 8 col-slices of 32
  const float* gi = dir ? giB : giF;
  const f16* Whh = dir ? WhhB : WhhF;
  const float* bhh = dir ? bhhB : bhhF;
  f16* hb = hpp + (size_t)dir * (2 * 64 * 256);
  int* flags = bar + dir * 8 * 16;

  int lo = lane & 15, hi = lane >> 4;
  int koff = hi * 8;
  int m = mTile * 16 + lo;
  int jb0 = ns * 32 + hi * 4;           // i=0 col base (4 consecutive)
  int aRow = mTile * 16 + lo;           // B-operand (h) row

  // zero ping-pong buffer 0 (sc1 so remote sc1 readers see it)
  {
    f16* z = hb + ((size_t)(w8 * 256 + tid)) * 8;
    st_z8(z); st_z8(z + 4);
  }

  // hoist step-invariant weights into registers (A-operand rows = gate cols)
  f16x8 wr[3][2][8];
#pragma unroll
  for (int q = 0; q < 3; q++)
#pragma unroll
    for (int i = 0; i < 2; i++)
#pragma unroll
      for (int ks = 0; ks < 8; ks++)
        wr[q][i][ks] = *(const f16x8*)(Whh + (size_t)(q * 256 + ns * 32 + i * 16 + lo) * 256 + ks * 32 + koff);
  // keepalive: prevent load sinking into the loop
#pragma unroll
  for (int q = 0; q < 3; q++)
#pragma unroll
    for (int i = 0; i < 2; i++)
#pragma unroll
      for (int ks = 0; ks < 8; ks++)
        asm volatile("" : "+v"(wr[q][i][ks]));

  float4 bh[3][2];
#pragma unroll
  for (int q = 0; q < 3; q++)
#pragma unroll
    for (int i = 0; i < 2; i++)
      bh[q][i] = *(const float4*)(bhh + q * 256 + jb0 + i * 16);

  float4 ho[2] = {};
  float4 gcur[3][2];
  {
    int s0 = dir ? 31 : 0;
    const float* g0 = gi + (size_t)s0 * (64 * 768);
#pragma unroll
    for (int q = 0; q < 3; q++)
#pragma unroll
      for (int i = 0; i < 2; i++)
        gcur[q][i] = *(const float4*)(g0 + (size_t)m * 768 + q * 256 + jb0 + i * 16);
  }

  fbar(flags, w8, 8, 1);
  for (int s = 0; s < 32; s++) {
    const f16* hr = hb + (s & 1) * (64 * 256);
    f16* hw = hb + ((s + 1) & 1) * (64 * 256);
    f16x8 af[8];
#pragma unroll
    for (int ks = 0; ks < 8; ks++)
      af[ks] = ld_h8(hr + aRow * 256 + ks * 32 + koff);
    f32x4 acc[3][2] = {};
#pragma unroll
    for (int ks = 0; ks < 8; ks++) {
#pragma unroll
      for (int q = 0; q < 3; q++)
#pragma unroll
        for (int i = 0; i < 2; i++)
          acc[q][i] = __builtin_amdgcn_mfma_f32_16x16x32_f16(wr[q][i][ks], af[ks], acc[q][i], 0, 0, 0);
    }
    float4 gn[3][2];
    {
      int sn = (s + 1 < 32) ? s + 1 : 31;
      int sgin = dir ? (31 - sn) : sn;
      const float* gs = gi + (size_t)sgin * (64 * 768);
#pragma unroll
      for (int q = 0; q < 3; q++)
#pragma unroll
        for (int i = 0; i < 2; i++)
          gn[q][i] = *(const float4*)(gs + (size_t)m * 768 + q * 256 + jb0 + i * 16);
    }
#pragma unroll
    for (int i = 0; i < 2; i++) {
      float hv[4];
#pragma unroll
      for (int r = 0; r < 4; r++) {
        float rg = sigmoidf_(((const float*)&gcur[0][i])[r] + acc[0][i][r] + ((const float*)&bh[0][i])[r]);
        float zg = sigmoidf_(((const float*)&gcur[1][i])[r] + acc[1][i][r] + ((const float*)&bh[1][i])[r]);
        float ng = tanhf_(((const float*)&gcur[2][i])[r] + rg * (acc[2][i][r] + ((const float*)&bh[2][i])[r]));
        float hprev = ((const float*)&ho[i])[r];
        hv[r] = (1.f - zg) * ng + zg * hprev;
        ((float*)&ho[i])[r] = hv[r];
      }
      if (s < 31) st_h4(hw + m * 256 + jb0 + i * 16, hv[0], hv[1], hv[2], hv[3]);
    }
#pragma unroll
    for (int q = 0; q < 3; q++)
#pragma unroll
      for (int i = 0; i < 2; i++) gcur[q][i] = gn[q][i];
    if (s < 31) fbar(flags, w8, 8, s + 2);
  }
  // context = [h_fwd, h_bwd] (plain stores; kernel boundary publishes)
#pragma unroll
  for (int i = 0; i < 2; i++) {
    int c = dir * 256 + jb0 + i * 16;
    *(float4*)(ctx32 + m * 512 + c) = ho[i];
    union { unsigned long long u; f16 h[4]; } t;
#pragma unroll
    for (int r = 0; r < 4; r++) t.h[r] = (f16)((const float*)&ho[i])[r];
    *(unsigned long long*)(ctx16 + m * 512 + c) = t.u;
  }
}

// ---------------- K6: decoder GRU recurrence (32 WGs x 256 thr) ----------------
// Swapped operands; weights register-resident (192 VGPR keepalive).
__global__ __launch_bounds__(256, 1) void k_dec(
    const float* __restrict__ giTok, const float* __restrict__ giCtx,
    const f16* __restrict__ Whh, const float* __restrict__ bhh,
    const float* __restrict__ ctx32, const f16* __restrict__ ctx16,
    f16* __restrict__ Hall, int* __restrict__ bar) {
  int wg = blockIdx.x;
  int tid = threadIdx.x, lane = tid & 63, wv = tid >> 6;
  int W = wg * 4 + wv;                  // [0,128)
  int mTile = W >> 5;                   // 4 m-tiles of 16 rows
  int cg = W & 31;                      // 32 col-slices of 16
  int* flags = bar + 16 * 16;

  int lo = lane & 15, hi = lane >> 4;
  int koff = hi * 8;
  int m = mTile * 16 + lo;
  int j0 = cg * 16 + hi * 4;            // 4 consecutive hidden cols
  int aRow = mTile * 16 + lo;

  // hoist step-invariant weights
  f16x8 wr[3][16];
#pragma unroll
  for (int q = 0; q < 3; q++)
#pragma unroll
    for (int ks = 0; ks < 16; ks++)
      wr[q][ks] = *(const f16x8*)(Whh + (size_t)(q * 512 + cg * 16 + lo) * 512 + ks * 32 + koff);
#pragma unroll
  for (int q = 0; q < 3; q++)
#pragma unroll
    for (int ks = 0; ks < 16; ks++)
      asm volatile("" : "+v"(wr[q][ks]));

  float4 bh[3], gc[3];
#pragma unroll
  for (int q = 0; q < 3; q++) {
    bh[q] = *(const float4*)(bhh + q * 512 + j0);
    gc[q] = *(const float4*)(giCtx + (size_t)m * 1536 + q * 512 + j0);
  }
  float4 ho = *(const float4*)(ctx32 + m * 512 + j0);
  float4 gcur[3];
#pragma unroll
  for (int q = 0; q < 3; q++)
    gcur[q] = *(const float4*)(giTok + (size_t)m * 1536 + q * 512 + j0);

  for (int t = 0; t < 31; t++) {
    const f16* hr = t ? (Hall + (size_t)(t - 1) * (64 * 512)) : ctx16;
    f16* hw = Hall + (size_t)t * (64 * 512);
    f16x8 af[16];
#pragma unroll
    for (int ks = 0; ks < 16; ks++)
      af[ks] = ld_h8(hr + aRow * 512 + ks * 32 + koff);
    f32x4 acc[3] = {};
#pragma unroll
    for (int ks = 0; ks < 16; ks++) {
#pragma unroll
      for (int q = 0; q < 3; q++)
        acc[q] = __builtin_amdgcn_mfma_f32_16x16x32_f16(wr[q][ks], af[ks], acc[q], 0, 0, 0);
    }
    float4 gn[3];
    {
      int tn = (t + 1 < 31) ? t + 1 : 30;
      const float* gs = giTok + (size_t)tn * (64 * 1536);
#pragma unroll
      for (int q = 0; q < 3; q++)
        gn[q] = *(const float4*)(gs + (size_t)m * 1536 + q * 512 + j0);
    }
    float hv[4];
#pragma unroll
    for (int r = 0; r < 4; r++) {
      float rg_ = sigmoidf_(((const float*)&gcur[0])[r] + ((const float*)&gc[0])[r] + acc[0][r] + ((const float*)&bh[0])[r]);
      float zg = sigmoidf_(((const float*)&gcur[1])[r] + ((const float*)&gc[1])[r] + acc[1][r] + ((const float*)&bh[1])[r]);
      float ng = tanhf_(((const float*)&gcur[2])[r] + ((const float*)&gc[2])[r] + rg_ * (acc[2][r] + ((const float*)&bh[2])[r]));
      float hprev = ((const float*)&ho)[r];
      hv[r] = (1.f - zg) * ng + zg * hprev;
      ((float*)&ho)[r] = hv[r];
    }
    st_h4(hw + m * 512 + j0, hv[0], hv[1], hv[2], hv[3]);
#pragma unroll
    for (int q = 0; q < 3; q++) gcur[q] = gn[q];
    if (t < 30) fbar(flags, wg, 32, t + 1);
  }
}

// ---------------- K7: FC GEMM  out[b, t+1, :] = Hall[t*64+b, :] @ fcW^T + fcb ----------------
// 128x128 tile, BK=64, XOR-swizzled LDS (kills 16-way bank conflict on ds_read_b128).
__global__ __launch_bounds__(256, 2) void k_fc(const f16* __restrict__ Hall, const f16* __restrict__ Wfc,
                                               const float* __restrict__ fcb, float* __restrict__ out) {
  __shared__ f16 As[128 * 64];
  __shared__ f16 Bs[128 * 64];
  int bid = blockIdx.x;
  int by = bid / 250, bx = bid % 250;
  int m0 = by * 128, n0 = bx * 128;
  int tid = threadIdx.x, lane = tid & 63, wv = tid >> 6;
  int wm = wv >> 1, wn = wv & 1;
  f32x4 acc[4][4] = {};
  for (int kk = 0; kk < 8; kk++) {
    f16x8 ra[4], rb[4];
#pragma unroll
    for (int c = 0; c < 4; c++) {
      int seg = c * 256 + tid;
      int row = seg >> 3, ko = (seg & 7) * 8;
      ra[c] = *(const f16x8*)(Hall + (size_t)(m0 + row) * 512 + kk * 64 + ko);
      rb[c] = *(const f16x8*)(Wfc + (size_t)(n0 + row) * 512 + kk * 64 + ko);
    }
    __syncthreads();
#pragma unroll
    for (int c = 0; c < 4; c++) {
      int seg = c * 256 + tid;
      int row = seg >> 3;
      int col = ((seg & 7) * 8) ^ ((row & 7) << 3);   // XOR swizzle
      *(f16x8*)&As[row * 64 + col] = ra[c];
      *(f16x8*)&Bs[row * 64 + col] = rb[c];
    }
    __syncthreads();
#pragma unroll
    for (int ks = 0; ks < 2; ks++) {
      f16x8 af[4], bf[4];
#pragma unroll
      for (int mi = 0; mi < 4; mi++) {
        int row = wm * 64 + mi * 16 + (lane & 15);
        int col = (ks * 32 + (lane >> 4) * 8) ^ ((row & 7) << 3);
        af[mi] = *(const f16x8*)&As[row * 64 + col];
      }
#pragma unroll
      for (int ni = 0; ni < 4; ni++) {
        int row = wn * 64 + ni * 16 + (lane & 15);
        int col = (ks * 32 + (lane >> 4) * 8) ^ ((row & 7) << 3);
        bf[ni] = *(const f16x8*)&Bs[row * 64 + col];
      }
#pragma unroll
      for (int mi = 0; mi < 4; mi++) {
#pragma unroll
        for (int ni = 0; ni < 4; ni++)
          acc[mi][ni] = __builtin_amdgcn_mfma_f32_16x16x32_f16(af[mi], bf[ni], acc[mi][ni], 0, 0, 0);
      }
    }
  }
  int dn0 = n0 + wn * 64 + (lane & 15);
  float bv[4];
#pragma unroll
  for (int ni = 0; ni < 4; ni++) bv[ni] = fcb[dn0 + ni * 16];
#pragma unroll
  for (int mi = 0; mi < 4; mi++) {
    int mbase = m0 + wm * 64 + mi * 16 + ((lane >> 4) << 2);
#pragma unroll
    for (int r = 0; r < 4; r++) {
      int mm = mbase + r;
      if (mm < 1984) {
        int t = mm >> 6, b = mm & 63;
        float* orow = out + (size_t)b * 1024000 + (size_t)(t + 1) * 32000;
#pragma unroll
        for (int ni = 0; ni < 4; ni++) orow[dn0 + ni * 16] = acc[mi][ni][r] + bv[ni];
      }
    }
  }
}

extern "C" void kernel_launch(void* const* d_in, const int* in_sizes, int n_in,
                              void* d_out, int out_size, void* d_ws, size_t ws_size,
                              hipStream_t stream) {
  const int*   srct = (const int*)d_in[0];
  const int*   trgt = (const int*)d_in[1];
  const float* embe = (const float*)d_in[2];
  const float* wihf = (const float*)d_in[3];
  const float* whhf = (const float*)d_in[4];
  const float* bihf = (const float*)d_in[5];
  const float* bhhf = (const float*)d_in[6];
  const float* wihb = (const float*)d_in[7];
  const float* whhb = (const float*)d_in[8];
  const float* bihb = (const float*)d_in[9];
  const float* bhhb = (const float*)d_in[10];
  const float* embd = (const float*)d_in[11];
  const float* wihd = (const float*)d_in[12];
  const float* whhd = (const float*)d_in[13];
  const float* bihd = (const float*)d_in[14];
  const float* bhhd = (const float*)d_in[15];
  const float* fcw  = (const float*)d_in[16];
  const float* fcb  = (const float*)d_in[17];
  float* out = (float*)d_out;
  char* ws = (char*)d_ws;

  f16* W_ihf = (f16*)(ws + OFF_WIHF);
  f16* W_hhf = (f16*)(ws + OFF_WHHF);
  f16* W_ihb = (f16*)(ws + OFF_WIHB);
  f16* W_hhb = (f16*)(ws + OFF_WHHB);
  f16* W_ihd = (f16*)(ws + OFF_WIHD);
  f16* W_hhd = (f16*)(ws + OFF_WHHD);
  f16* Wfc   = (f16*)(ws + OFF_FCW);
  f16* Xenc  = (f16*)(ws + OFF_XENC);
  f16* Xdec  = (f16*)(ws + OFF_XDEC);
  float* giF   = (float*)(ws + OFF_GIF);
  float* giB   = (float*)(ws + OFF_GIB);
  float* giTok = (float*)(ws + OFF_GITOK);
  float* giCtx = (float*)(ws + OFF_GICTX);
  float* ctx32 = (float*)(ws + OFF_CTX32);
  f16*   ctx16 = (f16*)(ws + OFF_CTX16);
  f16*   hpp   = (f16*)(ws + OFF_HPP);
  f16*   Hall  = (f16*)(ws + OFF_HALL);
  int*   bar   = (int*)(ws + OFF_BAR);

  k_convert<<<2048, 256, 0, stream>>>(wihf, whhf, wihb, whhb, wihd, whhd, fcw,
                                      W_ihf, W_hhf, W_ihb, W_hhb, W_ihd, W_hhd, Wfc);
  k_gather<<<1024, 256, 0, stream>>>(srct, trgt, embe, embd, Xenc, Xdec, out, bar);
  k_gemm<<<dim3(32, 12), 256, 0, stream>>>(Xenc, 256, W_ihf, 256, bihf, giF, 768, 8);
  k_gemm<<<dim3(32, 12), 256, 0, stream>>>(Xenc, 256, W_ihb, 256, bihb, giB, 768, 8);
  k_gemm<<<dim3(31, 24), 256, 0, stream>>>(Xdec, 256, W_ihd, 768, nullptr, giTok, 1536, 8);
  k_enc<<<16, 256, 0, stream>>>(giF, giB, W_hhf, W_hhb, bhhf, bhhb, hpp, ctx32, ctx16, bar);
  k_gemm<<<dim3(1, 24), 256, 0, stream>>>(ctx16, 512, W_ihd + 256, 768, bihd, giCtx, 1536, 16);
  k_dec<<<32, 256, 0, stream>>>(giTok, giCtx, W_hhd, bhhd, ctx32, ctx16, Hall, bar);
  k_fc<<<4000, 256, 0, stream>>>(Hall, Wfc, fcb, out);
}

// Round 5
// 608.155 us; speedup vs baseline: 1.0926x; 1.0926x over previous
//
#include <hip/hip_runtime.h>
#include <cmath>

typedef _Float16 f16;
typedef _Float16 f16x4 __attribute__((ext_vector_type(4)));
typedef _Float16 f16x8 __attribute__((ext_vector_type(8)));
typedef float f32x4 __attribute__((ext_vector_type(4)));
typedef unsigned long long u64;

// Dims: V=32000 E=256 H=256 B=64 S=32 T=32; decoder hidden 2H=512.
static constexpr u64 SENT = 0xFFFFFFFFFFFFFFFFULL;  // f16x4 all-NaN; real h never NaN

// ---------------- workspace layout (bytes) ----------------
static constexpr size_t OFF_WIHF = 0;                                 // 768x256 f16
static constexpr size_t OFF_WHHF = OFF_WIHF + 768UL*256*2;
static constexpr size_t OFF_WIHB = OFF_WHHF + 768UL*256*2;
static constexpr size_t OFF_WHHB = OFF_WIHB + 768UL*256*2;
static constexpr size_t OFF_WIHD = OFF_WHHB + 768UL*256*2;            // 1536x768 f16
static constexpr size_t OFF_WHHD = OFF_WIHD + 1536UL*768*2;           // 1536x512 f16
static constexpr size_t OFF_FCW  = OFF_WHHD + 1536UL*512*2;           // 32000x512 f16
static constexpr size_t OFF_XENC = OFF_FCW  + 32000UL*512*2;          // 2048x256 f16
static constexpr size_t OFF_XDEC = OFF_XENC + 2048UL*256*2;           // 1984x256 f16
static constexpr size_t OFF_GIF  = OFF_XDEC + 1984UL*256*2;           // 2048x768 f32
static constexpr size_t OFF_GIB  = OFF_GIF  + 2048UL*768*4;
static constexpr size_t OFF_GITOK= OFF_GIB  + 2048UL*768*4;           // 1984x1536 f32
static constexpr size_t OFF_CTX32= OFF_GITOK+ 1984UL*1536*4;          // 64x512 f32
static constexpr size_t OFF_CTX16= OFF_CTX32+ 64UL*512*4;             // 64x512 f16
static constexpr size_t OFF_HPP  = OFF_CTX16+ 64UL*512*2;             // [2dir][32step][64][256] f16
static constexpr size_t OFF_HALL = OFF_HPP  + 2UL*32*64*256*2;        // 2048x512 f16 (31 slots + pad)

__device__ __forceinline__ float sigmoidf_(float x) {
  return __builtin_amdgcn_rcpf(1.f + __expf(-x));
}
__device__ __forceinline__ float tanhf_(float x) {
  float xc = fminf(fmaxf(x, -10.f), 10.f);
  float e = __expf(2.f * xc);
  return (e - 1.f) * __builtin_amdgcn_rcpf(e + 1.f);
}

// Device-coherent (sc1, L3-mediated) 8B atomic accessors — the only cross-WG path.
__device__ __forceinline__ u64 ldsc1(const u64* p) {
  return __hip_atomic_load(p, __ATOMIC_RELAXED, __HIP_MEMORY_SCOPE_AGENT);
}
__device__ __forceinline__ void stsc1(u64* p, u64 v) {
  __hip_atomic_store(p, v, __ATOMIC_RELAXED, __HIP_MEMORY_SCOPE_AGENT);
}
__device__ __forceinline__ void sth4(f16* p, float a, float b, float c, float d) {
  union { u64 u; f16 h[4]; } t;
  t.h[0] = (f16)a; t.h[1] = (f16)b; t.h[2] = (f16)c; t.h[3] = (f16)d;
  stsc1((u64*)p, t.u);
}

// ---------------- K1: init (embedding gather + weight fp16 convert + sentinels) ----------------
__global__ void k_init(const int* __restrict__ srct, const int* __restrict__ trgt,
                       const float* __restrict__ embe, const float* __restrict__ embd,
                       const float* __restrict__ wihf, const float* __restrict__ whhf,
                       const float* __restrict__ wihb, const float* __restrict__ whhb,
                       const float* __restrict__ wihd, const float* __restrict__ whhd,
                       const float* __restrict__ fcw,
                       f16* dWihf, f16* dWhhf, f16* dWihb, f16* dWhhb,
                       f16* dWihd, f16* dWhhd, f16* dFcw,
                       f16* __restrict__ Xenc, f16* __restrict__ Xdec,
                       f16* __restrict__ hpp, f16* __restrict__ Hall,
                       float* __restrict__ out) {
  int b = blockIdx.x, tid = threadIdx.x;
  if (b < 1024) {
    long t = (long)b * 256 + tid;       // [0, 262144)
    const long stride = 1024L * 256;
    // embedding gather -> f16
    for (long i = t; i < 4032L * 64; i += stride) {
      int row = (int)(i >> 6), j4 = (int)(i & 63);
      const float* e; f16* d; int tok;
      if (row < 2048) {
        int s = row >> 6, bb = row & 63;
        tok = srct[bb * 32 + s]; e = embe; d = Xenc + (long)row * 256;
      } else {
        int rd = row - 2048; int tt = rd >> 6, bb = rd & 63;
        tok = trgt[bb * 32 + tt]; e = embd; d = Xdec + (long)rd * 256;
      }
      float4 v = ((const float4*)(e + (long)tok * 256))[j4];
      f16x4 o; o.x = (f16)v.x; o.y = (f16)v.y; o.z = (f16)v.z; o.w = (f16)v.w;
      ((f16x4*)d)[j4] = o;
    }
    // zero out[:, 0, :]
    for (long i = t; i < 64L * 8000; i += stride) {
      long bb = i / 8000, j = i % 8000;
      ((float4*)(out + bb * 1024000L))[j] = make_float4(0.f, 0.f, 0.f, 0.f);
    }
    // sentinel Hall slots 0..30 (rows 0..1983): 253952 u64
    u64* H8 = (u64*)Hall;
    if (t < 253952) H8[t] = SENT;
    // hpp: step-0 buffers zero; steps 1..31 sentinel. dir stride = 131072 u64.
    u64* P8 = (u64*)hpp;
    if (t < 4096) { P8[t] = 0ULL; P8[131072 + t] = 0ULL; }
    if (t < 126976) { P8[4096 + t] = SENT; P8[131072 + 4096 + t] = SENT; }
  } else {
    // fp32 -> fp16 weight conversion (float4 granules, 4784128 total)
    long cb = b - 1024;                  // [0, 4672)
    const long stride = 4672L * 256;
    for (long i = cb * 256 + tid; i < 4784128L; i += stride) {
      const float* s; f16* d; long j = i;
      if (j < 49152L)        { s = wihf; d = dWihf; }
      else if (j < 98304L)   { s = whhf; d = dWhhf; j -= 49152L; }
      else if (j < 147456L)  { s = wihb; d = dWihb; j -= 98304L; }
      else if (j < 196608L)  { s = whhb; d = dWhhb; j -= 147456L; }
      else if (j < 491520L)  { s = wihd; d = dWihd; j -= 196608L; }
      else if (j < 688128L)  { s = whhd; d = dWhhd; j -= 491520L; }
      else                   { s = fcw;  d = dFcw;  j -= 688128L; }
      float4 v = ((const float4*)s)[j];
      f16x4 o; o.x = (f16)v.x; o.y = (f16)v.y; o.z = (f16)v.z; o.w = (f16)v.w;
      ((f16x4*)d)[j] = o;
    }
  }
}

// ---------------- shared GEMM body: C[M,N] = A[M,K]f16 @ B[N,K]f16^T (+bias) ----------------
__device__ __forceinline__ void gemm_body(int bx, int by,
                                          const f16* __restrict__ A, int lda,
                                          const f16* __restrict__ B, int ldb,
                                          const float* __restrict__ bias,
                                          float* __restrict__ C, int ldc, int Ksteps) {
  int m0 = bx * 64, n0 = by * 64;
  int lane = threadIdx.x & 63, w = threadIdx.x >> 6;
  int ar = m0 + w * 16 + (lane & 15);
  int koff = (lane >> 4) * 8;
  f32x4 acc[4] = {};
  for (int ks = 0; ks < Ksteps; ks++) {
    f16x8 a = *(const f16x8*)(A + (size_t)ar * lda + ks * 32 + koff);
#pragma unroll
    for (int ni = 0; ni < 4; ni++) {
      const f16* bp = B + (size_t)(n0 + ni * 16 + (lane & 15)) * ldb + ks * 32 + koff;
      f16x8 bfr = *(const f16x8*)bp;
      acc[ni] = __builtin_amdgcn_mfma_f32_16x16x32_f16(a, bfr, acc[ni], 0, 0, 0);
    }
  }
  int dm = m0 + w * 16 + ((lane >> 4) << 2);
  int dn0 = n0 + (lane & 15);
#pragma unroll
  for (int ni = 0; ni < 4; ni++) {
    int n = dn0 + ni * 16;
    float bv = bias ? bias[n] : 0.f;
#pragma unroll
    for (int r = 0; r < 4; r++) C[(size_t)(dm + r) * ldc + n] = acc[ni][r] + bv;
  }
}

// ---------------- K2: fused input-side GEMMs (giF | giB | giTok) ----------------
__global__ __launch_bounds__(256) void k_gi(const f16* __restrict__ Xenc, const f16* __restrict__ Xdec,
                                            const f16* __restrict__ Wf, const f16* __restrict__ Wb,
                                            const f16* __restrict__ Wd,
                                            const float* __restrict__ bf, const float* __restrict__ bb,
                                            float* __restrict__ giF, float* __restrict__ giB,
                                            float* __restrict__ giTok) {
  int b = blockIdx.x;
  if (b < 384)      gemm_body(b & 31, b >> 5, Xenc, 256, Wf, 256, bf, giF, 768, 8);
  else if (b < 768) { b -= 384; gemm_body(b & 31, b >> 5, Xenc, 256, Wb, 256, bb, giB, 768, 8); }
  else              { b -= 768; gemm_body(b % 31, b / 31, Xdec, 256, Wd, 768, nullptr, giTok, 1536, 8); }
}

// ---------------- K3: encoder bidir GRU — dataflow sync, no barriers ----------------
// Wave (dir, mTile, ns): rows mTile*16..+16, cols ns*32..+32. hpp[dir][s] is
// step s's h (step-0 buffer pre-zeroed, others sentinel). Consumers spin on data.
__global__ __launch_bounds__(256, 1) void k_enc(
    const float* __restrict__ giF, const float* __restrict__ giB,
    const f16* __restrict__ WhhF, const f16* __restrict__ WhhB,
    const float* __restrict__ bhhF, const float* __restrict__ bhhB,
    f16* __restrict__ hpp, float* __restrict__ ctx32, f16* __restrict__ ctx16) {
  int wg = blockIdx.x;
  int dir = wg >> 3, r = wg & 7;
  int mTile = r >> 1, pw = r & 1;
  int tid = threadIdx.x, lane = tid & 63, wv = tid >> 6;
  int ns = pw * 4 + wv;
  const float* gi = dir ? giB : giF;
  const f16* Whh = dir ? WhhB : WhhF;
  const float* bhh = dir ? bhhB : bhhF;
  f16* hb = hpp + (size_t)dir * (32 * 64 * 256);
  int lo = lane & 15, hi = lane >> 4;
  int koff = hi * 8;
  int m = mTile * 16 + lo;
  int jb0 = ns * 32 + hi * 4;

  float4 bh[3][2];
#pragma unroll
  for (int q = 0; q < 3; q++)
#pragma unroll
    for (int i = 0; i < 2; i++)
      bh[q][i] = *(const float4*)(bhh + q * 256 + jb0 + i * 16);

  float4 ho[2] = {};
  float4 gcur[3][2];
  {
    int s0 = dir ? 31 : 0;
    const float* g0 = gi + (size_t)s0 * (64 * 768);
#pragma unroll
    for (int q = 0; q < 3; q++)
#pragma unroll
      for (int i = 0; i < 2; i++)
        gcur[q][i] = *(const float4*)(g0 + (size_t)m * 768 + q * 256 + jb0 + i * 16);
  }

  for (int s = 0; s < 32; s++) {
    // issue next-step gi prefetch first (independent of h)
    float4 gn[3][2];
    {
      int sn = (s + 1 < 32) ? s + 1 : 31;
      int sgin = dir ? (31 - sn) : sn;
      const float* gs = gi + (size_t)sgin * (64 * 768);
#pragma unroll
      for (int q = 0; q < 3; q++)
#pragma unroll
        for (int i = 0; i < 2; i++)
          gn[q][i] = *(const float4*)(gs + (size_t)m * 768 + q * 256 + jb0 + i * 16);
    }
    // spin-load h[s] (own 16 rows, own K-slice); step-0 buffer holds real zeros
    const u64* h8 = (const u64*)(hb + (size_t)s * 16384) + (size_t)m * 64 + hi * 2;
    u64 hv[16];
#pragma unroll
    for (int i = 0; i < 16; i++) hv[i] = SENT;
    bool done = false;
    while (!done) {
      done = true;
#pragma unroll
      for (int ks = 0; ks < 8; ks++)
#pragma unroll
        for (int j = 0; j < 2; j++) {
          int ix = ks * 2 + j;
          if (hv[ix] == SENT) {
            u64 x = ldsc1(h8 + ks * 8 + j);
            hv[ix] = x;
            if (x == SENT) done = false;
          }
        }
      if (!done) __builtin_amdgcn_s_sleep(1);
    }
    f32x4 acc[3][2] = {};
#pragma unroll
    for (int ks = 0; ks < 8; ks++) {
      union { u64 u[2]; f16x8 v; } a;
      a.u[0] = hv[ks * 2]; a.u[1] = hv[ks * 2 + 1];
#pragma unroll
      for (int q = 0; q < 3; q++)
#pragma unroll
        for (int i = 0; i < 2; i++) {
          f16x8 w = *(const f16x8*)(Whh + (size_t)(q * 256 + ns * 32 + i * 16 + lo) * 256 + ks * 32 + koff);
          acc[q][i] = __builtin_amdgcn_mfma_f32_16x16x32_f16(w, a.v, acc[q][i], 0, 0, 0);
        }
    }
#pragma unroll
    for (int i = 0; i < 2; i++) {
      float hvv[4];
#pragma unroll
      for (int r2 = 0; r2 < 4; r2++) {
        float rg = sigmoidf_(((const float*)&gcur[0][i])[r2] + acc[0][i][r2] + ((const float*)&bh[0][i])[r2]);
        float zg = sigmoidf_(((const float*)&gcur[1][i])[r2] + acc[1][i][r2] + ((const float*)&bh[1][i])[r2]);
        float ng = tanhf_(((const float*)&gcur[2][i])[r2] + rg * (acc[2][i][r2] + ((const float*)&bh[2][i])[r2]));
        float hprev = ((const float*)&ho[i])[r2];
        hvv[r2] = (1.f - zg) * ng + zg * hprev;
        ((float*)&ho[i])[r2] = hvv[r2];
      }
      if (s < 31) sth4(hb + (size_t)(s + 1) * 16384 + m * 256 + jb0 + i * 16,
                       hvv[0], hvv[1], hvv[2], hvv[3]);
    }
#pragma unroll
    for (int q = 0; q < 3; q++)
#pragma unroll
      for (int i = 0; i < 2; i++) gcur[q][i] = gn[q][i];
  }
  // context = [h_fwd, h_bwd] (plain stores; kernel boundary publishes)
#pragma unroll
  for (int i = 0; i < 2; i++) {
    int c = dir * 256 + jb0 + i * 16;
    *(float4*)(ctx32 + m * 512 + c) = ho[i];
    union { u64 u; f16 h[4]; } t;
#pragma unroll
    for (int r2 = 0; r2 < 4; r2++) t.h[r2] = (f16)((const float*)&ho[i])[r2];
    *(u64*)(ctx16 + m * 512 + c) = t.u;
  }
}

// ---------------- K4: decoder GRU — dataflow sync, no barriers; giCtx fused in prologue ----------------
// Wave (mTile, cg): rows mTile*16..+16, cols cg*16..+16. Hall[t] per-step slots.
__global__ __launch_bounds__(256, 1) void k_dec(
    const float* __restrict__ giTok, const f16* __restrict__ Wihd, const float* __restrict__ bihd,
    const f16* __restrict__ Whh, const float* __restrict__ bhh,
    const float* __restrict__ ctx32, const f16* __restrict__ ctx16,
    f16* __restrict__ Hall) {
  int wg = blockIdx.x;
  int mTile = wg >> 3, r = wg & 7;
  int tid = threadIdx.x, lane = tid & 63, wv = tid >> 6;
  int cg = r * 4 + wv;
  int lo = lane & 15, hi = lane >> 4;
  int koff = hi * 8;
  int m = mTile * 16 + lo;
  int j0 = cg * 16 + hi * 4;

  // prologue: giCtx = ctx @ W_ihd[:,256:].T via MFMA (replaces separate GEMM)
  f32x4 acx[3] = {};
#pragma unroll
  for (int ks = 0; ks < 16; ks++) {
    f16x8 a = *(const f16x8*)(ctx16 + (size_t)m * 512 + ks * 32 + koff);
#pragma unroll
    for (int q = 0; q < 3; q++) {
      f16x8 w = *(const f16x8*)(Wihd + (size_t)(q * 512 + cg * 16 + lo) * 768 + 256 + ks * 32 + koff);
      acx[q] = __builtin_amdgcn_mfma_f32_16x16x32_f16(w, a, acx[q], 0, 0, 0);
    }
  }
  // gate-constant terms. NOTE: b_hh_n must stay INSIDE the r* term; giCtx_n + b_ih_n outside.
  float b0[4], b1[4], bo2[4], bhn[4];
#pragma unroll
  for (int r2 = 0; r2 < 4; r2++) {
    b0[r2]  = acx[0][r2] + bihd[j0 + r2]        + bhh[j0 + r2];
    b1[r2]  = acx[1][r2] + bihd[512 + j0 + r2]  + bhh[512 + j0 + r2];
    bo2[r2] = acx[2][r2] + bihd[1024 + j0 + r2];
    bhn[r2] = bhh[1024 + j0 + r2];
  }
  float4 ho = *(const float4*)(ctx32 + m * 512 + j0);
  float4 gcur[3];
#pragma unroll
  for (int q = 0; q < 3; q++)
    gcur[q] = *(const float4*)(giTok + (size_t)m * 1536 + q * 512 + j0);

  for (int t = 0; t < 31; t++) {
    // next-step token-gi prefetch (independent of h)
    float4 gn[3];
    {
      int tn = (t + 1 < 31) ? t + 1 : 30;
      const float* gs = giTok + (size_t)tn * (64 * 1536);
#pragma unroll
      for (int q = 0; q < 3; q++)
        gn[q] = *(const float4*)(gs + (size_t)m * 1536 + q * 512 + j0);
    }
    // h operand: t=0 from ctx16 (plain, kernel boundary); else spin on Hall[t-1]
    u64 hv[32];
    if (t == 0) {
      const u64* c8 = (const u64*)ctx16 + (size_t)m * 128 + hi * 2;
#pragma unroll
      for (int ks = 0; ks < 16; ks++)
#pragma unroll
        for (int j = 0; j < 2; j++) hv[ks * 2 + j] = c8[ks * 8 + j];
    } else {
      const u64* h8 = (const u64*)(Hall + (size_t)(t - 1) * 32768) + (size_t)m * 128 + hi * 2;
#pragma unroll
      for (int i = 0; i < 32; i++) hv[i] = SENT;
      bool done = false;
      while (!done) {
        done = true;
#pragma unroll
        for (int ks = 0; ks < 16; ks++)
#pragma unroll
          for (int j = 0; j < 2; j++) {
            int ix = ks * 2 + j;
            if (hv[ix] == SENT) {
              u64 x = ldsc1(h8 + ks * 8 + j);
              hv[ix] = x;
              if (x == SENT) done = false;
            }
          }
        if (!done) __builtin_amdgcn_s_sleep(1);
      }
    }
    f32x4 acc[3] = {};
#pragma unroll
    for (int ks = 0; ks < 16; ks++) {
      union { u64 u[2]; f16x8 v; } a;
      a.u[0] = hv[ks * 2]; a.u[1] = hv[ks * 2 + 1];
#pragma unroll
      for (int q = 0; q < 3; q++) {
        f16x8 w = *(const f16x8*)(Whh + (size_t)(q * 512 + cg * 16 + lo) * 512 + ks * 32 + koff);
        acc[q] = __builtin_amdgcn_mfma_f32_16x16x32_f16(w, a.v, acc[q], 0, 0, 0);
      }
    }
    float hvv[4];
#pragma unroll
    for (int r2 = 0; r2 < 4; r2++) {
      float rg = sigmoidf_(((const float*)&gcur[0])[r2] + acc[0][r2] + b0[r2]);
      float zg = sigmoidf_(((const float*)&gcur[1])[r2] + acc[1][r2] + b1[r2]);
      float ng = tanhf_(((const float*)&gcur[2])[r2] + bo2[r2] + rg * (acc[2][r2] + bhn[r2]));
      float hprev = ((const float*)&ho)[r2];
      hvv[r2] = (1.f - zg) * ng + zg * hprev;
      ((float*)&ho)[r2] = hvv[r2];
    }
    sth4(Hall + (size_t)t * 32768 + (size_t)m * 512 + j0, hvv[0], hvv[1], hvv[2], hvv[3]);
#pragma unroll
    for (int q = 0; q < 3; q++) gcur[q] = gn[q];
  }
}

// ---------------- K5: FC GEMM  out[b, t+1, :] = Hall[t*64+b, :] @ fcW^T + fcb ----------------
__global__ __launch_bounds__(256, 2) void k_fc(const f16* __restrict__ Hall, const f16* __restrict__ Wfc,
                                               const float* __restrict__ fcb, float* __restrict__ out) {
  __shared__ f16 As[128 * 64];
  __shared__ f16 Bs[128 * 64];
  int bid = blockIdx.x;
  int by = bid / 250, bx = bid % 250;
  int m0 = by * 128, n0 = bx * 128;
  int tid = threadIdx.x, lane = tid & 63, wv = tid >> 6;
  int wm = wv >> 1, wn = wv & 1;
  f32x4 acc[4][4] = {};
  for (int kk = 0; kk < 8; kk++) {
    f16x8 ra[4], rb[4];
#pragma unroll
    for (int c = 0; c < 4; c++) {
      int seg = c * 256 + tid;
      int row = seg >> 3, ko = (seg & 7) * 8;
      ra[c] = *(const f16x8*)(Hall + (size_t)(m0 + row) * 512 + kk * 64 + ko);
      rb[c] = *(const f16x8*)(Wfc + (size_t)(n0 + row) * 512 + kk * 64 + ko);
    }
    __syncthreads();
#pragma unroll
    for (int c = 0; c < 4; c++) {
      int seg = c * 256 + tid;
      int row = seg >> 3;
      int col = ((seg & 7) * 8) ^ ((row & 7) << 3);   // XOR swizzle
      *(f16x8*)&As[row * 64 + col] = ra[c];
      *(f16x8*)&Bs[row * 64 + col] = rb[c];
    }
    __syncthreads();
#pragma unroll
    for (int ks = 0; ks < 2; ks++) {
      f16x8 af[4], bf[4];
#pragma unroll
      for (int mi = 0; mi < 4; mi++) {
        int row = wm * 64 + mi * 16 + (lane & 15);
        int col = (ks * 32 + (lane >> 4) * 8) ^ ((row & 7) << 3);
        af[mi] = *(const f16x8*)&As[row * 64 + col];
      }
#pragma unroll
      for (int ni = 0; ni < 4; ni++) {
        int row = wn * 64 + ni * 16 + (lane & 15);
        int col = (ks * 32 + (lane >> 4) * 8) ^ ((row & 7) << 3);
        bf[ni] = *(const f16x8*)&Bs[row * 64 + col];
      }
#pragma unroll
      for (int mi = 0; mi < 4; mi++) {
#pragma unroll
        for (int ni = 0; ni < 4; ni++)
          acc[mi][ni] = __builtin_amdgcn_mfma_f32_16x16x32_f16(af[mi], bf[ni], acc[mi][ni], 0, 0, 0);
      }
    }
  }
  int dn0 = n0 + wn * 64 + (lane & 15);
  float bv[4];
#pragma unroll
  for (int ni = 0; ni < 4; ni++) bv[ni] = fcb[dn0 + ni * 16];
#pragma unroll
  for (int mi = 0; mi < 4; mi++) {
    int mbase = m0 + wm * 64 + mi * 16 + ((lane >> 4) << 2);
#pragma unroll
    for (int rr = 0; rr < 4; rr++) {
      int mm = mbase + rr;
      if (mm < 1984) {
        int t = mm >> 6, bb = mm & 63;
        float* orow = out + (size_t)bb * 1024000 + (size_t)(t + 1) * 32000;
#pragma unroll
        for (int ni = 0; ni < 4; ni++) orow[dn0 + ni * 16] = acc[mi][ni][rr] + bv[ni];
      }
    }
  }
}

extern "C" void kernel_launch(void* const* d_in, const int* in_sizes, int n_in,
                              void* d_out, int out_size, void* d_ws, size_t ws_size,
                              hipStream_t stream) {
  const int*   srct = (const int*)d_in[0];
  const int*   trgt = (const int*)d_in[1];
  const float* embe = (const float*)d_in[2];
  const float* wihf = (const float*)d_in[3];
  const float* whhf = (const float*)d_in[4];
  const float* bihf = (const float*)d_in[5];
  const float* bhhf = (const float*)d_in[6];
  const float* wihb = (const float*)d_in[7];
  const float* whhb = (const float*)d_in[8];
  const float* bihb = (const float*)d_in[9];
  const float* bhhb = (const float*)d_in[10];
  const float* embd = (const float*)d_in[11];
  const float* wihd = (const float*)d_in[12];
  const float* whhd = (const float*)d_in[13];
  const float* bihd = (const float*)d_in[14];
  const float* bhhd = (const float*)d_in[15];
  const float* fcw  = (const float*)d_in[16];
  const float* fcb  = (const float*)d_in[17];
  float* out = (float*)d_out;
  char* ws = (char*)d_ws;

  f16* W_ihf = (f16*)(ws + OFF_WIHF);
  f16* W_hhf = (f16*)(ws + OFF_WHHF);
  f16* W_ihb = (f16*)(ws + OFF_WIHB);
  f16* W_hhb = (f16*)(ws + OFF_WHHB);
  f16* W_ihd = (f16*)(ws + OFF_WIHD);
  f16* W_hhd = (f16*)(ws + OFF_WHHD);
  f16* Wfc   = (f16*)(ws + OFF_FCW);
  f16* Xenc  = (f16*)(ws + OFF_XENC);
  f16* Xdec  = (f16*)(ws + OFF_XDEC);
  float* giF   = (float*)(ws + OFF_GIF);
  float* giB   = (float*)(ws + OFF_GIB);
  float* giTok = (float*)(ws + OFF_GITOK);
  float* ctx32 = (float*)(ws + OFF_CTX32);
  f16*   ctx16 = (f16*)(ws + OFF_CTX16);
  f16*   hpp   = (f16*)(ws + OFF_HPP);
  f16*   Hall  = (f16*)(ws + OFF_HALL);

  k_init<<<5696, 256, 0, stream>>>(srct, trgt, embe, embd,
                                   wihf, whhf, wihb, whhb, wihd, whhd, fcw,
                                   W_ihf, W_hhf, W_ihb, W_hhb, W_ihd, W_hhd, Wfc,
                                   Xenc, Xdec, hpp, Hall, out);
  k_gi<<<1512, 256, 0, stream>>>(Xenc, Xdec, W_ihf, W_ihb, W_ihd, bihf, bihb,
                                 giF, giB, giTok);
  k_enc<<<16, 256, 0, stream>>>(giF, giB, W_hhf, W_hhb, bhhf, bhhb, hpp, ctx32, ctx16);
  k_dec<<<32, 256, 0, stream>>>(giTok, W_ihd, bihd, W_hhd, bhhd, ctx32, ctx16, Hall);
  k_fc<<<4000, 256, 0, stream>>>(Hall, Wfc, fcb, out);
}